// Round 9
// baseline (173.319 us; speedup 1.0000x reference)
//
#include <hip/hip_runtime.h>
#include <hip/hip_bf16.h>
#include <stdint.h>

typedef unsigned short u16;
typedef __bf16 bf16x8 __attribute__((ext_vector_type(8)));
typedef float f32x4 __attribute__((ext_vector_type(4)));
typedef unsigned short u16x4 __attribute__((ext_vector_type(4)));

#define BM 128
#define BN 128
#define BK 32

__device__ inline float bf2f(u16 v) {
    return __builtin_bit_cast(float, (uint32_t)v << 16);
}
__device__ inline u16 f2bf(float v) {
    return __builtin_bit_cast(u16, (__bf16)v);
}
__device__ inline void gll16(const void* src, const char* lds_dst) {
    __builtin_amdgcn_global_load_lds(
        (const __attribute__((address_space(1))) void*)src,
        (__attribute__((address_space(3))) void*)lds_dst, 16, 0, 0);
}

// XCD-bijective remap. CONVENTION (R7 post-mortem): launch dim3(n_M_tiles,
// n_N_tiles) so nby == gridDim.y. by = N-tile, bx = M-tile. Same-XCD
// dispatch chunk sweeps all by for consecutive bx (A-panel L2 locality).
__device__ inline void xcd_remap(int nby, int& bx, int& by) {
    const int lin = (int)blockIdx.x + (int)blockIdx.y * (int)gridDim.x;
    const int g = lin & 7, s = lin >> 3;
    by = s % nby;
    bx = (s / nby) * 8 + g;
}

// ---------------------------------------------------------------------------
// LDS swizzle (R6-verified, conflicts 4.2M -> 0): bf16 tile [128][32] has
// 4 granules of 16B per row; involution g' = g ^ ((row>>1)&3) closed over
// 2 bits. Staging rows step +64, fragment rows +16 -> (row>>1)&3 invariant
// per thread. Source pre-swizzled, read XORs the granule (rule #21).
// ---------------------------------------------------------------------------

// ---------------------------------------------------------------------------
// GEMM: C[M][N] = A[M][K](bf16) @ Bt[N][K]^T(bf16); CT = u16 (bf16 C) or f32.
// m97 single-buffer structure + gll16 both operands + swizzle + XCD remap.
// ---------------------------------------------------------------------------
template <typename CT>
__global__ __launch_bounds__(256) void gemm_bt(
    const u16* __restrict__ A, const u16* __restrict__ Bt,
    CT* __restrict__ C, int M, int N, int K)
{
    __shared__ u16 Al[BM * BK];
    __shared__ u16 Bl[BN * BK];
    int bx, by; xcd_remap((int)gridDim.y, bx, by);

    const int tid  = threadIdx.x;
    const int wave = tid >> 6;
    const int lane = tid & 63;
    const int wr   = wave >> 1;
    const int wc   = wave & 1;

    // staging: thread t -> linear LDS slot t (row=t>>2, granule=t&3);
    // source granule pre-swizzled: (t&3) ^ ((row>>1)&3), row>>1 = t>>3
    const int srow = tid >> 2;
    const int skk  = (((tid & 3) ^ ((tid >> 3) & 3)) << 3);

    const u16* abase0 = A + (long)(bx * BM + srow) * K + skk;
    const u16* abase1 = abase0 + (long)64 * K;
    const u16* bbase0 = Bt + (long)(by * BN + srow) * K + skk;
    const u16* bbase1 = bbase0 + (long)64 * K;

    char* alds = (char*)&Al[0];
    char* blds = (char*)&Bl[0];
    const int wslot = wave * 1024;

    f32x4 acc[4][4];
#pragma unroll
    for (int i = 0; i < 4; ++i)
#pragma unroll
        for (int j = 0; j < 4; ++j) acc[i][j] = (f32x4){0.f, 0.f, 0.f, 0.f};

    // fragment reads: row = (wr|wc)*64 + fr + m*16, natural granule cg=lane>>4
    // -> read LDS granule cg ^ ((fr>>1)&3)
    const int fr  = lane & 15;
    const int cg  = lane >> 4;
    const int swz = ((cg ^ ((fr >> 1) & 3)) << 3);
    const int aoff = (wr * 64 + fr) * BK + swz;
    const int boff = (wc * 64 + fr) * BK + swz;

    for (int kt = 0; kt < K; kt += BK) {
        gll16(abase0 + kt, alds + wslot);
        gll16(abase1 + kt, alds + 4096 + wslot);
        gll16(bbase0 + kt, blds + wslot);
        gll16(bbase1 + kt, blds + 4096 + wslot);
        __syncthreads();   // drain vmcnt -> tile visible

        bf16x8 af[4], bfg[4];
#pragma unroll
        for (int m = 0; m < 4; ++m)
            af[m] = *(const bf16x8*)&Al[aoff + m * 16 * BK];
#pragma unroll
        for (int n = 0; n < 4; ++n)
            bfg[n] = *(const bf16x8*)&Bl[boff + n * 16 * BK];
#pragma unroll
        for (int m = 0; m < 4; ++m)
#pragma unroll
            for (int n = 0; n < 4; ++n)
                acc[m][n] = __builtin_amdgcn_mfma_f32_16x16x32_bf16(
                    af[m], bfg[n], acc[m][n], 0, 0, 0);
        __syncthreads();   // reads done before next stage overwrites
    }

    // C/D layout: col = lane&15, row = (lane>>4)*4 + j
    const int crow = bx * BM + wr * 64 + (lane >> 4) * 4;
    const int ccol = by * BN + wc * 64 + (lane & 15);
#pragma unroll
    for (int m = 0; m < 4; ++m)
#pragma unroll
        for (int n = 0; n < 4; ++n)
#pragma unroll
            for (int j = 0; j < 4; ++j) {
                const long idx = (long)(crow + m * 16 + j) * N + (ccol + n * 16);
                if constexpr (__is_same(CT, float))
                    C[idx] = acc[m][n][j];
                else
                    C[idx] = f2bf(acc[m][n][j]);
            }
}

// ---------------------------------------------------------------------------
// fused 3-layer EMA scan (R2-verified): bf16 in/out, SCHUNK=128, LOOK=256,
// double-buffered 8-deep register prefetch.
// ---------------------------------------------------------------------------
#define SCHUNK 128
#define SLOOK  256

__device__ inline float sigmoidf_(float x) { return 1.f / (1.f + __expf(-x)); }

__global__ __launch_bounds__(256) void ema3_scan_bf(
    const u16* __restrict__ h, const float* __restrict__ log_a,
    u16* __restrict__ h3)
{
    const int t = (int)blockIdx.x * 256 + (int)threadIdx.x;  // 65536 threads
    const int e     = t & 511;
    const int b     = (t >> 9) & 3;
    const int chunk = t >> 11;           // 0..31
    const float a1 = sigmoidf_(log_a[e]);
    const float a2 = sigmoidf_(log_a[512 + e]);
    const float a3 = sigmoidf_(log_a[1024 + e]);
    const float c1 = 1.f - a1, c2 = 1.f - a2, c3 = 1.f - a3;
    const long base = ((long)b * 4096) * 512 + e;
    const int l0 = chunk * SCHUNK;
    const int ls = (l0 - SLOOK > 0) ? (l0 - SLOOK) : 0;
    const int S  = l0 + SCHUNK - ls;     // 128 / 256 / 384 — all /16
    const u16* hp = h + base + (long)ls * 512;
    u16* op = h3 + base + (long)ls * 512;
    int gl = ls;
    float y1 = 0.f, y2 = 0.f, y3 = 0.f;

    u16 A[8], B[8];
#pragma unroll
    for (int i = 0; i < 8; ++i) A[i] = hp[(long)i * 512];
    hp += 8 * 512;

    const int nb = S >> 4;
    for (int ib = 0; ib < nb; ++ib) {
#pragma unroll
        for (int i = 0; i < 8; ++i) B[i] = hp[(long)i * 512];
        hp += 8 * 512;
#pragma unroll
        for (int i = 0; i < 8; ++i) {
            const float v = bf2f(A[i]);
            y1 = a1 * y1 + c1 * v;
            y2 = a2 * y2 + c2 * y1;
            y3 = a3 * y3 + c3 * y2;
            if (gl >= l0) *op = f2bf(y3);
            op += 512; ++gl;
        }
        // over-reads up to 8 rows past chunk end (in-bounds: h sits at
        // d_out+64MiB inside the 128MiB region; values never consumed)
#pragma unroll
        for (int i = 0; i < 8; ++i) A[i] = hp[(long)i * 512];
        hp += 8 * 512;
#pragma unroll
        for (int i = 0; i < 8; ++i) {
            const float v = bf2f(B[i]);
            y1 = a1 * y1 + c1 * v;
            y2 = a2 * y2 + c2 * y1;
            y3 = a3 * y3 + c3 * y2;
            if (gl >= l0) *op = f2bf(y3);
            op += 512; ++gl;
        }
    }
}

// ---------------------------------------------------------------------------
// x f32 -> bf16, float4 in / 8B out
// ---------------------------------------------------------------------------
__global__ __launch_bounds__(256) void cvt_f32_to_bf16(
    const float* __restrict__ in, u16* __restrict__ out, int n4)
{
    int i = (int)blockIdx.x * 256 + (int)threadIdx.x;
    const int stride = (int)gridDim.x * 256;
    for (; i < n4; i += stride) {
        const float4 v = reinterpret_cast<const float4*>(in)[i];
        u16x4 o;
        o[0] = f2bf(v.x); o[1] = f2bf(v.y); o[2] = f2bf(v.z); o[3] = f2bf(v.w);
        reinterpret_cast<u16x4*>(out)[i] = o;
    }
}

// ---------------------------------------------------------------------------
// both weight matrices f32 -> bf16 in one launch (1M f32 each)
// ---------------------------------------------------------------------------
__global__ __launch_bounds__(256) void cvt_weights(
    const float* __restrict__ wd, const float* __restrict__ wu,
    u16* __restrict__ wd_o, u16* __restrict__ wu_o, int n4each)
{
    int i = (int)blockIdx.x * 256 + (int)threadIdx.x;
    const int stride = (int)gridDim.x * 256;
    for (; i < 2 * n4each; i += stride) {
        const float* in = (i < n4each) ? wd : wu;
        u16* out = (i < n4each) ? wd_o : wu_o;
        const int j = (i < n4each) ? i : (i - n4each);
        const float4 v = reinterpret_cast<const float4*>(in)[j];
        u16x4 o;
        o[0] = f2bf(v.x); o[1] = f2bf(v.y); o[2] = f2bf(v.z); o[3] = f2bf(v.w);
        reinterpret_cast<u16x4*>(out)[j] = o;
    }
}

// ---------------------------------------------------------------------------
// B=4, L=4096, D=2048, Di=512. Scratch plan:
//   d_out[0:64MiB)   = x_bf16     (dead before GEMM2 writes d_out)
//   d_out[64:80MiB)  = h (bf16)   (dead before GEMM2 writes d_out)
//   d_ws[0:2MiB)     = W_down bf16
//   d_ws[2:4MiB)     = W_up   bf16
//   d_ws[4:20MiB)    = h3 bf16
// ---------------------------------------------------------------------------
extern "C" void kernel_launch(void* const* d_in, const int* in_sizes, int n_in,
                              void* d_out, int out_size, void* d_ws, size_t ws_size,
                              hipStream_t stream)
{
    const float* x      = (const float*)d_in[0];
    const float* W_down = (const float*)d_in[1];
    const float* W_up   = (const float*)d_in[2];
    const float* log_a  = (const float*)d_in[3];
    float* out = (float*)d_out;

    u16*   x_bf  = (u16*)d_out;
    u16*   h_bf  = (u16*)((char*)d_out + (64u << 20));
    u16*   Wd_bf = (u16*)d_ws;
    u16*   Wu_bf = (u16*)((char*)d_ws + (2u << 20));
    u16*   h3    = (u16*)((char*)d_ws + (4u << 20));

    cvt_f32_to_bf16<<<4096, 256, 0, stream>>>(x, x_bf, (4 * 4096 * 2048) / 4);
    cvt_weights<<<512, 256, 0, stream>>>(W_down, W_up, Wd_bf, Wu_bf,
                                         (512 * 2048) / 4);

    // h = x_bf @ W_down^T  (M=16384, N=512, K=2048)
    // grid = dim3(n_M_tiles=128, n_N_tiles=4)  [xcd_remap convention]
    gemm_bt<u16><<<dim3(128, 4), 256, 0, stream>>>(
        x_bf, Wd_bf, h_bf, 16384, 512, 2048);

    // 3-layer EMA scan, bf16 in/out
    ema3_scan_bf<<<256, 256, 0, stream>>>(h_bf, log_a, h3);

    // out = h3 @ W_up^T  (M=16384, N=2048, K=512)
    // grid = dim3(n_M_tiles=128, n_N_tiles=16)
    gemm_bt<float><<<dim3(128, 16), 256, 0, stream>>>(
        h3, Wu_bf, out, 16384, 2048, 512);
}

// Round 10
// 154.639 us; speedup vs baseline: 1.1208x; 1.1208x over previous
//
#include <hip/hip_runtime.h>
#include <hip/hip_bf16.h>
#include <stdint.h>

typedef unsigned short u16;
typedef __bf16 bf16x8 __attribute__((ext_vector_type(8)));
typedef float f32x4 __attribute__((ext_vector_type(4)));
typedef unsigned short u16x4 __attribute__((ext_vector_type(4)));

#define BM 128
#define BN 128
#define BK 64

__device__ inline float bf2f(u16 v) {
    return __builtin_bit_cast(float, (uint32_t)v << 16);
}
__device__ inline u16 f2bf(float v) {
    return __builtin_bit_cast(u16, (__bf16)v);
}
__device__ inline void gll16(const void* src, const char* lds_dst) {
    __builtin_amdgcn_global_load_lds(
        (const __attribute__((address_space(1))) void*)src,
        (__attribute__((address_space(3))) void*)lds_dst, 16, 0, 0);
}

// XCD-bijective remap. CONVENTION (R7): launch dim3(n_M_tiles, n_N_tiles) so
// nby == gridDim.y. by = N-tile, bx = M-tile. Same-XCD dispatch chunk sweeps
// all by for consecutive bx (A-panel L2 locality).
__device__ inline void xcd_remap(int nby, int& bx, int& by) {
    const int lin = (int)blockIdx.x + (int)blockIdx.y * (int)gridDim.x;
    const int g = lin & 7, s = lin >> 3;
    by = s % nby;
    bx = (s / nby) * 8 + g;
}

// ---------------------------------------------------------------------------
// LDS swizzle for bf16 tile [128][64] (128B rows -> bank index is
// row-independent): 8 granules of 16B per row, involution g' = g ^ (row&7),
// closed over 3 bits (round-5 lesson). Staging rows step +32, fragment rows
// +16 -> row&7 == fr&7 invariant per thread. Source pre-swizzled, read XORs
// the granule (rule #21 both-sides). 16 lanes cover 8 granules x 2 = all 32
// banks 2-way = free (m136).
// ---------------------------------------------------------------------------

// ---------------------------------------------------------------------------
// GEMM: C[M][N] = A[M][K](bf16) @ Bt[N][K]^T(bf16); CT = u16 (bf16 C) or f32.
// m97 single-buffer structure, BK=64 (drain amortization), gll16 staging,
// swizzle, XCD remap. Per iter: 8 gll16, 16 ds_read_b128, 32 MFMA.
// ---------------------------------------------------------------------------
template <typename CT>
__global__ __launch_bounds__(256) void gemm_bt(
    const u16* __restrict__ A, const u16* __restrict__ Bt,
    CT* __restrict__ C, int M, int N, int K)
{
    __shared__ u16 Al[BM * BK];   // 16 KiB
    __shared__ u16 Bl[BN * BK];   // 16 KiB
    int bx, by; xcd_remap((int)gridDim.y, bx, by);

    const int tid  = threadIdx.x;
    const int wave = tid >> 6;
    const int lane = tid & 63;
    const int wr   = wave >> 1;
    const int wc   = wave & 1;

    // staging: 4 rounds per operand; round rd covers rows rd*32 + (t>>3);
    // thread owns granule t&7, source granule pre-swizzled with row&7=(t>>3)&7
    const int srow = tid >> 3;                       // 0..31
    const int sg   = (tid & 7) ^ ((tid >> 3) & 7);   // source granule
    const u16* abase = A  + (long)(bx * BM + srow) * K + sg * 8;
    const u16* bbase = Bt + (long)(by * BN + srow) * K + sg * 8;

    char* alds = (char*)&Al[0];
    char* blds = (char*)&Bl[0];
    const int wslot = wave * 1024;

    f32x4 acc[4][4];
#pragma unroll
    for (int i = 0; i < 4; ++i)
#pragma unroll
        for (int j = 0; j < 4; ++j) acc[i][j] = (f32x4){0.f, 0.f, 0.f, 0.f};

    // fragment reads: row = (wr|wc)*64 + fr + m*16; k-step kk in {0,1};
    // natural granule = kk*4 + (lane>>4); read LDS granule ^ (fr&7)
    const int fr  = lane & 15;
    const int cg  = lane >> 4;
    const int rx  = fr & 7;
    const int arow0 = (wr * 64 + fr) * BK;
    const int brow0 = (wc * 64 + fr) * BK;

    for (int kt = 0; kt < K; kt += BK) {
#pragma unroll
        for (int rd = 0; rd < 4; ++rd) {
            gll16(abase + kt + (long)rd * 32 * K, alds + rd * 4096 + wslot);
            gll16(bbase + kt + (long)rd * 32 * K, blds + rd * 4096 + wslot);
        }
        __syncthreads();   // drain vmcnt -> tile visible

#pragma unroll
        for (int kk = 0; kk < 2; ++kk) {
            const int goff = (((kk << 2) + cg) ^ rx) << 3;
            bf16x8 af[4], bfg[4];
#pragma unroll
            for (int m = 0; m < 4; ++m)
                af[m] = *(const bf16x8*)&Al[arow0 + m * 16 * BK + goff];
#pragma unroll
            for (int n = 0; n < 4; ++n)
                bfg[n] = *(const bf16x8*)&Bl[brow0 + n * 16 * BK + goff];
#pragma unroll
            for (int m = 0; m < 4; ++m)
#pragma unroll
                for (int n = 0; n < 4; ++n)
                    acc[m][n] = __builtin_amdgcn_mfma_f32_16x16x32_bf16(
                        af[m], bfg[n], acc[m][n], 0, 0, 0);
        }
        __syncthreads();   // reads done before next stage overwrites
    }

    // C/D layout: col = lane&15, row = (lane>>4)*4 + j
    const int crow = bx * BM + wr * 64 + (lane >> 4) * 4;
    const int ccol = by * BN + wc * 64 + (lane & 15);
#pragma unroll
    for (int m = 0; m < 4; ++m)
#pragma unroll
        for (int n = 0; n < 4; ++n)
#pragma unroll
            for (int j = 0; j < 4; ++j) {
                const long idx = (long)(crow + m * 16 + j) * N + (ccol + n * 16);
                if constexpr (__is_same(CT, float))
                    C[idx] = acc[m][n][j];
                else
                    C[idx] = f2bf(acc[m][n][j]);
            }
}

// ---------------------------------------------------------------------------
// fused 3-layer EMA scan: bf16 in/out, SCHUNK=64 (512 blocks, R4-verified),
// LOOK=256, double-buffered 8-deep register prefetch.
// ---------------------------------------------------------------------------
#define SCHUNK 64
#define SLOOK  256

__device__ inline float sigmoidf_(float x) { return 1.f / (1.f + __expf(-x)); }

__global__ __launch_bounds__(256) void ema3_scan_bf(
    const u16* __restrict__ h, const float* __restrict__ log_a,
    u16* __restrict__ h3)
{
    const int t = (int)blockIdx.x * 256 + (int)threadIdx.x;  // 131072 threads
    const int e     = t & 511;
    const int b     = (t >> 9) & 3;
    const int chunk = t >> 11;           // 0..63
    const float a1 = sigmoidf_(log_a[e]);
    const float a2 = sigmoidf_(log_a[512 + e]);
    const float a3 = sigmoidf_(log_a[1024 + e]);
    const float c1 = 1.f - a1, c2 = 1.f - a2, c3 = 1.f - a3;
    const long base = ((long)b * 4096) * 512 + e;
    const int l0 = chunk * SCHUNK;
    const int ls = (l0 - SLOOK > 0) ? (l0 - SLOOK) : 0;
    const int S  = l0 + SCHUNK - ls;     // 64..320, all /16
    const u16* hp = h + base + (long)ls * 512;
    u16* op = h3 + base + (long)ls * 512;
    int gl = ls;
    float y1 = 0.f, y2 = 0.f, y3 = 0.f;

    u16 A[8], B[8];
#pragma unroll
    for (int i = 0; i < 8; ++i) A[i] = hp[(long)i * 512];
    hp += 8 * 512;

    const int nb = S >> 4;
    for (int ib = 0; ib < nb; ++ib) {
#pragma unroll
        for (int i = 0; i < 8; ++i) B[i] = hp[(long)i * 512];
        hp += 8 * 512;
#pragma unroll
        for (int i = 0; i < 8; ++i) {
            const float v = bf2f(A[i]);
            y1 = a1 * y1 + c1 * v;
            y2 = a2 * y2 + c2 * y1;
            y3 = a3 * y3 + c3 * y2;
            if (gl >= l0) *op = f2bf(y3);
            op += 512; ++gl;
        }
        // over-reads up to 8 rows past chunk end (in-bounds: h sits at
        // d_out+64MiB inside the 128MiB region; values never consumed)
#pragma unroll
        for (int i = 0; i < 8; ++i) A[i] = hp[(long)i * 512];
        hp += 8 * 512;
#pragma unroll
        for (int i = 0; i < 8; ++i) {
            const float v = bf2f(B[i]);
            y1 = a1 * y1 + c1 * v;
            y2 = a2 * y2 + c2 * y1;
            y3 = a3 * y3 + c3 * y2;
            if (gl >= l0) *op = f2bf(y3);
            op += 512; ++gl;
        }
    }
}

// ---------------------------------------------------------------------------
// x f32 -> bf16, float4 in / 8B out (HBM-roofline: ~30 us)
// ---------------------------------------------------------------------------
__global__ __launch_bounds__(256) void cvt_f32_to_bf16(
    const float* __restrict__ in, u16* __restrict__ out, int n4)
{
    int i = (int)blockIdx.x * 256 + (int)threadIdx.x;
    const int stride = (int)gridDim.x * 256;
    for (; i < n4; i += stride) {
        const float4 v = reinterpret_cast<const float4*>(in)[i];
        u16x4 o;
        o[0] = f2bf(v.x); o[1] = f2bf(v.y); o[2] = f2bf(v.z); o[3] = f2bf(v.w);
        reinterpret_cast<u16x4*>(out)[i] = o;
    }
}

// ---------------------------------------------------------------------------
// both weight matrices f32 -> bf16 in one launch (1M f32 each)
// ---------------------------------------------------------------------------
__global__ __launch_bounds__(256) void cvt_weights(
    const float* __restrict__ wd, const float* __restrict__ wu,
    u16* __restrict__ wd_o, u16* __restrict__ wu_o, int n4each)
{
    int i = (int)blockIdx.x * 256 + (int)threadIdx.x;
    const int stride = (int)gridDim.x * 256;
    for (; i < 2 * n4each; i += stride) {
        const float* in = (i < n4each) ? wd : wu;
        u16* out = (i < n4each) ? wd_o : wu_o;
        const int j = (i < n4each) ? i : (i - n4each);
        const float4 v = reinterpret_cast<const float4*>(in)[j];
        u16x4 o;
        o[0] = f2bf(v.x); o[1] = f2bf(v.y); o[2] = f2bf(v.z); o[3] = f2bf(v.w);
        reinterpret_cast<u16x4*>(out)[j] = o;
    }
}

// ---------------------------------------------------------------------------
// B=4, L=4096, D=2048, Di=512. Scratch plan:
//   d_out[0:64MiB)   = x_bf16     (dead before GEMM2 writes d_out)
//   d_out[64:80MiB)  = h (bf16)   (dead before GEMM2 writes d_out)
//   d_ws[0:2MiB)     = W_down bf16
//   d_ws[2:4MiB)     = W_up   bf16
//   d_ws[4:20MiB)    = h3 bf16
// ---------------------------------------------------------------------------
extern "C" void kernel_launch(void* const* d_in, const int* in_sizes, int n_in,
                              void* d_out, int out_size, void* d_ws, size_t ws_size,
                              hipStream_t stream)
{
    const float* x      = (const float*)d_in[0];
    const float* W_down = (const float*)d_in[1];
    const float* W_up   = (const float*)d_in[2];
    const float* log_a  = (const float*)d_in[3];
    float* out = (float*)d_out;

    u16*   x_bf  = (u16*)d_out;
    u16*   h_bf  = (u16*)((char*)d_out + (64u << 20));
    u16*   Wd_bf = (u16*)d_ws;
    u16*   Wu_bf = (u16*)((char*)d_ws + (2u << 20));
    u16*   h3    = (u16*)((char*)d_ws + (4u << 20));

    cvt_f32_to_bf16<<<4096, 256, 0, stream>>>(x, x_bf, (4 * 4096 * 2048) / 4);
    cvt_weights<<<512, 256, 0, stream>>>(W_down, W_up, Wd_bf, Wu_bf,
                                         (512 * 2048) / 4);

    // h = x_bf @ W_down^T  (M=16384, N=512, K=2048)
    // grid = dim3(n_M_tiles=128, n_N_tiles=4)  [xcd_remap convention]
    gemm_bt<u16><<<dim3(128, 4), 256, 0, stream>>>(
        x_bf, Wd_bf, h_bf, 16384, 512, 2048);

    // 3-layer EMA scan, bf16 in/out
    ema3_scan_bf<<<512, 256, 0, stream>>>(h_bf, log_a, h3);

    // out = h3 @ W_up^T  (M=16384, N=2048, K=512)
    // grid = dim3(n_M_tiles=128, n_N_tiles=16)
    gemm_bt<float><<<dim3(128, 16), 256, 0, stream>>>(
        h3, Wu_bf, out, 16384, 2048, 512);
}